// Round 1
// baseline (332.205 us; speedup 1.0000x reference)
//
#include <hip/hip_runtime.h>

// ST-BIF multi-step neuron, T=4 timesteps carried in registers.
// x: [T, N] with N = B*L*D = 16*1024*768 = 12,582,912 fp32 elements per step.
// Each thread owns 4 consecutive spatial elements (float4) and runs the
// 4-step recurrence for them. Fully coalesced loads/stores; HBM-bound.

#define TSTEPS 4

__global__ __launch_bounds__(256) void stbif_ms_kernel(
    const float4* __restrict__ x,      // [TSTEPS * n4] float4
    const float*  __restrict__ qthr,   // scalar
    float4*       __restrict__ out,    // [TSTEPS * n4] float4
    int n4)                            // float4 count per timestep
{
    const int i = blockIdx.x * 256 + threadIdx.x;
    if (i >= n4) return;

    const float vth = *qthr;

    // Preload all timesteps (independent loads, overlap latency).
    float4 xt[TSTEPS];
#pragma unroll
    for (int t = 0; t < TSTEPS; ++t)
        xt[t] = x[(size_t)t * (size_t)n4 + (size_t)i];

    const float POS_MAX = 15.0f;
    const float NEG_MIN = 0.0f;

    float v[4], tc[4];
#pragma unroll
    for (int c = 0; c < 4; ++c) { v[c] = 0.5f * vth; tc[c] = 0.0f; }

    float4 o[TSTEPS];
#pragma unroll
    for (int t = 0; t < TSTEPS; ++t) {
        const float* xp = (const float*)&xt[t];
        float* op = (float*)&o[t];
#pragma unroll
        for (int c = 0; c < 4; ++c) {
            const float H = v[c] + xp[c];
            const bool pos = (H >= vth)  && (tc[c] < POS_MAX);
            const bool neg = (H < 0.0f)  && (tc[c] > NEG_MIN);
            const float spike = pos ? 1.0f : (neg ? -1.0f : 0.0f);
            v[c]  = H - spike * vth;
            tc[c] = tc[c] + spike;
            op[c] = spike * vth;
        }
    }

#pragma unroll
    for (int t = 0; t < TSTEPS; ++t)
        out[(size_t)t * (size_t)n4 + (size_t)i] = o[t];
}

extern "C" void kernel_launch(void* const* d_in, const int* in_sizes, int n_in,
                              void* d_out, int out_size, void* d_ws, size_t ws_size,
                              hipStream_t stream) {
    const float* x    = (const float*)d_in[0];
    const float* qthr = (const float*)d_in[1];
    // d_in[2] = num_steps (known: 4)
    float* out = (float*)d_out;

    const int total = in_sizes[0];          // T*B*L*D = 50,331,648
    const int n     = total / TSTEPS;       // spatial elements per step
    const int n4    = n / 4;                // float4 per step = 3,145,728

    const int block = 256;
    const int grid  = (n4 + block - 1) / block;  // 12288 blocks

    stbif_ms_kernel<<<grid, block, 0, stream>>>(
        (const float4*)x, qthr, (float4*)out, n4);
}

// Round 3
// 322.041 us; speedup vs baseline: 1.0316x; 1.0316x over previous
//
#include <hip/hip_runtime.h>

// ST-BIF multi-step neuron, T=4 timesteps carried in registers.
// x: [T, N] with N = B*L*D = 16*1024*768 = 12,582,912 fp32 elements per step.
// Each thread owns 4 consecutive spatial elements and runs the 4-step
// recurrence in registers. Pure streaming (zero reuse) -> nontemporal
// loads/stores (nt bit) to avoid L2 allocate/evict churn on the 402 MB stream.
// Note: __builtin_nontemporal_* needs a native clang vector type, not HIP's
// float4 struct — use ext_vector_type(4).

#define TSTEPS 4

typedef float fx4 __attribute__((ext_vector_type(4)));

__global__ __launch_bounds__(256) void stbif_ms_kernel(
    const fx4* __restrict__ x,      // [TSTEPS * n4] float-x4
    const float* __restrict__ qthr, // scalar
    fx4* __restrict__ out,          // [TSTEPS * n4] float-x4
    int n4)                         // float4 count per timestep
{
    const int i = blockIdx.x * 256 + threadIdx.x;
    if (i >= n4) return;

    const float vth = *qthr;

    // Preload all timesteps nontemporally (independent loads, overlap latency).
    fx4 xt[TSTEPS];
#pragma unroll
    for (int t = 0; t < TSTEPS; ++t)
        xt[t] = __builtin_nontemporal_load(&x[(size_t)t * (size_t)n4 + (size_t)i]);

    const float POS_MAX = 15.0f;
    const float NEG_MIN = 0.0f;

    float v[4], tc[4];
#pragma unroll
    for (int c = 0; c < 4; ++c) { v[c] = 0.5f * vth; tc[c] = 0.0f; }

#pragma unroll
    for (int t = 0; t < TSTEPS; ++t) {
        fx4 o;
#pragma unroll
        for (int c = 0; c < 4; ++c) {
            const float H = v[c] + xt[t][c];
            const bool pos = (H >= vth)  && (tc[c] < POS_MAX);
            const bool neg = (H < 0.0f)  && (tc[c] > NEG_MIN);
            const float spike = pos ? 1.0f : (neg ? -1.0f : 0.0f);
            v[c]  = H - spike * vth;
            tc[c] = tc[c] + spike;
            o[c]  = spike * vth;
        }
        __builtin_nontemporal_store(o, &out[(size_t)t * (size_t)n4 + (size_t)i]);
    }
}

extern "C" void kernel_launch(void* const* d_in, const int* in_sizes, int n_in,
                              void* d_out, int out_size, void* d_ws, size_t ws_size,
                              hipStream_t stream) {
    const float* x    = (const float*)d_in[0];
    const float* qthr = (const float*)d_in[1];
    // d_in[2] = num_steps (known: 4)
    float* out = (float*)d_out;

    const int total = in_sizes[0];          // T*B*L*D = 50,331,648
    const int n     = total / TSTEPS;       // spatial elements per step
    const int n4    = n / 4;                // float4 per step = 3,145,728

    const int block = 256;
    const int grid  = (n4 + block - 1) / block;  // 12288 blocks

    stbif_ms_kernel<<<grid, block, 0, stream>>>(
        (const fx4*)x, qthr, (fx4*)out, n4);
}

// Round 4
// 320.151 us; speedup vs baseline: 1.0377x; 1.0059x over previous
//
#include <hip/hip_runtime.h>

// ST-BIF multi-step neuron, T=4 timesteps carried in registers.
// x: [T, N] with N = B*L*D = 12,582,912 fp32 per step.
// Each thread owns 8 spatial elements (2 float4s, 256-float4 apart so every
// load/store instruction is a fully-coalesced 1 KiB wave-chunk) and runs the
// 4-step recurrence in registers. 8 outstanding nt loads per thread for MLP.
// Pure streaming (zero reuse) -> nontemporal loads/stores (nt bit).

#define TSTEPS 4

typedef float fx4 __attribute__((ext_vector_type(4)));

__global__ __launch_bounds__(256) void stbif_ms_kernel(
    const fx4* __restrict__ x,      // [TSTEPS * n4]
    const float* __restrict__ qthr, // scalar
    fx4* __restrict__ out,          // [TSTEPS * n4]
    int n4)                         // float4 count per timestep
{
    // Each block covers 512 consecutive float4s: lanes take i0 = base+tid and
    // i1 = base+tid+256.
    const int base = blockIdx.x * 512 + threadIdx.x;
    const int i0 = base;
    const int i1 = base + 256;
    // n4 = 3,145,728 is divisible by 512 -> no tail guard needed, but keep a
    // cheap one for safety.
    if (i1 >= n4 + 256) return;

    const float vth = *qthr;

    // Preload all timesteps x both chunks nontemporally (8 independent loads).
    fx4 xa[TSTEPS], xb[TSTEPS];
#pragma unroll
    for (int t = 0; t < TSTEPS; ++t) {
        const size_t off = (size_t)t * (size_t)n4;
        xa[t] = __builtin_nontemporal_load(&x[off + (size_t)i0]);
        xb[t] = __builtin_nontemporal_load(&x[off + (size_t)i1]);
    }

    const float POS_MAX = 15.0f;
    const float NEG_MIN = 0.0f;

    float v[8], tc[8];
#pragma unroll
    for (int c = 0; c < 8; ++c) { v[c] = 0.5f * vth; tc[c] = 0.0f; }

#pragma unroll
    for (int t = 0; t < TSTEPS; ++t) {
        fx4 oa, ob;
#pragma unroll
        for (int c = 0; c < 4; ++c) {
            const float H = v[c] + xa[t][c];
            const bool pos = (H >= vth) && (tc[c] < POS_MAX);
            const bool neg = (H < 0.0f) && (tc[c] > NEG_MIN);
            const float spike = pos ? 1.0f : (neg ? -1.0f : 0.0f);
            v[c]  = H - spike * vth;
            tc[c] = tc[c] + spike;
            oa[c] = spike * vth;
        }
#pragma unroll
        for (int c = 0; c < 4; ++c) {
            const float H = v[4 + c] + xb[t][c];
            const bool pos = (H >= vth) && (tc[4 + c] < POS_MAX);
            const bool neg = (H < 0.0f) && (tc[4 + c] > NEG_MIN);
            const float spike = pos ? 1.0f : (neg ? -1.0f : 0.0f);
            v[4 + c]  = H - spike * vth;
            tc[4 + c] = tc[4 + c] + spike;
            ob[c] = spike * vth;
        }
        const size_t off = (size_t)t * (size_t)n4;
        __builtin_nontemporal_store(oa, &out[off + (size_t)i0]);
        __builtin_nontemporal_store(ob, &out[off + (size_t)i1]);
    }
}

extern "C" void kernel_launch(void* const* d_in, const int* in_sizes, int n_in,
                              void* d_out, int out_size, void* d_ws, size_t ws_size,
                              hipStream_t stream) {
    const float* x    = (const float*)d_in[0];
    const float* qthr = (const float*)d_in[1];
    // d_in[2] = num_steps (known: 4)
    float* out = (float*)d_out;

    const int total = in_sizes[0];          // T*B*L*D = 50,331,648
    const int n     = total / TSTEPS;       // spatial elements per step
    const int n4    = n / 4;                // float4 per step = 3,145,728

    const int block = 256;
    const int grid  = (n4 + 511) / 512;     // 6144 blocks, 2 float4s/thread

    stbif_ms_kernel<<<grid, block, 0, stream>>>(
        (const fx4*)x, qthr, (fx4*)out, n4);
}